// Round 1
// baseline (3557.683 us; speedup 1.0000x reference)
//
#include <hip/hip_runtime.h>

// Problem constants (B=32, S=512, C=256, H=8, NC=4, KW=7)
#define BB 32
#define SS 512
#define CC 256
#define NH 8
#define NCV 4
#define KW 7

#define TILE 64
#define KT 16
#define LDP (TILE + 4)   // +4 pad: breaks bank conflicts, keeps float4 alignment

// ---------------------------------------------------------------------------
// Generic f32 GEMM: C[bz] = epilogue(alpha * A[bz] @ (B or B^T)[bz])
// flags: bit0 = relu (after bias), bit1 = accumulate into existing C
// bias: length-N vector or nullptr; resid: MxN matrix or nullptr
// All of M,N divisible by 64; K divisible by 16 (true for every call here).
// ---------------------------------------------------------------------------
template<bool TRANSB>
__global__ __launch_bounds__(256)
void gemm_kernel(const float* __restrict__ A, const float* __restrict__ B,
                 float* __restrict__ C, int M, int N, int K,
                 int lda, int ldb, int ldc,
                 long long sA, long long sB, long long sC,
                 const float* __restrict__ bias,
                 const float* __restrict__ resid, long long sR, int ldr,
                 float alpha, int flags)
{
    __shared__ float As[KT][LDP];
    __shared__ float Bs[KT][LDP];
    const int bz = blockIdx.z;
    A += bz * sA;
    B += bz * sB;
    C += bz * sC;
    const float* Rp = resid ? resid + bz * sR : nullptr;

    const int m0 = blockIdx.x * TILE, n0 = blockIdx.y * TILE;
    const int t  = threadIdx.x;
    const int tr = t >> 4, tc = t & 15;      // 16x16 thread grid, 4x4 microtile
    const int kA = t & 15, mA = t >> 4;      // A-load coords

    float acc[4][4] = {};

    for (int k0 = 0; k0 < K; k0 += KT) {
        // A tile: 64 rows x 16 k, store transposed As[k][m]
        #pragma unroll
        for (int i = 0; i < 4; ++i) {
            int m = mA + i * 16;
            As[kA][m] = A[(long long)(m0 + m) * lda + (k0 + kA)];
        }
        // B tile: 16 k x 64 n
        if (!TRANSB) {
            #pragma unroll
            for (int i = 0; i < 4; ++i) {
                int kk = (t >> 6) + i * 4, nn = t & 63;
                Bs[kk][nn] = B[(long long)(k0 + kk) * ldb + (n0 + nn)];
            }
        } else {
            #pragma unroll
            for (int i = 0; i < 4; ++i) {
                int kk = t & 15, nn = (t >> 4) + i * 16;
                Bs[kk][nn] = B[(long long)(n0 + nn) * ldb + (k0 + kk)];
            }
        }
        __syncthreads();
        #pragma unroll
        for (int kk = 0; kk < KT; ++kk) {
            float4 a4 = *(const float4*)&As[kk][tr * 4];
            float4 b4 = *(const float4*)&Bs[kk][tc * 4];
            float ar[4] = {a4.x, a4.y, a4.z, a4.w};
            float br[4] = {b4.x, b4.y, b4.z, b4.w};
            #pragma unroll
            for (int i = 0; i < 4; ++i)
                #pragma unroll
                for (int j = 0; j < 4; ++j)
                    acc[i][j] += ar[i] * br[j];
        }
        __syncthreads();
    }

    // epilogue
    float4 bb = make_float4(0.f, 0.f, 0.f, 0.f);
    if (bias) bb = *(const float4*)&bias[n0 + tc * 4];
    #pragma unroll
    for (int i = 0; i < 4; ++i) {
        int gm = m0 + tr * 4 + i;
        float v0 = alpha * acc[i][0] + bb.x;
        float v1 = alpha * acc[i][1] + bb.y;
        float v2 = alpha * acc[i][2] + bb.z;
        float v3 = alpha * acc[i][3] + bb.w;
        if (flags & 1) {
            v0 = fmaxf(v0, 0.f); v1 = fmaxf(v1, 0.f);
            v2 = fmaxf(v2, 0.f); v3 = fmaxf(v3, 0.f);
        }
        if (Rp) {
            float4 rr = *(const float4*)&Rp[(long long)gm * ldr + n0 + tc * 4];
            v0 += rr.x; v1 += rr.y; v2 += rr.z; v3 += rr.w;
        }
        float* cp = &C[(long long)gm * ldc + n0 + tc * 4];
        if (flags & 2) {
            float4 cc = *(const float4*)cp;
            v0 += cc.x; v1 += cc.y; v2 += cc.z; v3 += cc.w;
        }
        *(float4*)cp = make_float4(v0, v1, v2, v3);
    }
}

// ---------------------------------------------------------------------------
// Conv1d (k=7, same pad) as gather-GEMM: out[b,s,co] =
//   bias[co] + resid[b,s,co] + sum_{kw,ci} H[b,s+kw-3,ci] * W[kw*C+ci, co]
// M = B*S = 16384, N = C = 256, K = KW*C = 1792
// ---------------------------------------------------------------------------
__global__ __launch_bounds__(256)
void conv_gemm_kernel(const float* __restrict__ H, const float* __restrict__ W,
                      const float* __restrict__ bias,
                      const float* __restrict__ resid, float* __restrict__ C)
{
    __shared__ float As[KT][LDP];
    __shared__ float Bs[KT][LDP];
    const int m0 = blockIdx.x * TILE, n0 = blockIdx.y * TILE;
    const int t  = threadIdx.x;
    const int tr = t >> 4, tc = t & 15;
    const int kA = t & 15, mA = t >> 4;

    float acc[4][4] = {};

    for (int k0 = 0; k0 < KW * CC; k0 += KT) {
        int kg = k0 + kA;
        int kw = kg >> 8, ci = kg & (CC - 1);
        #pragma unroll
        for (int i = 0; i < 4; ++i) {
            int gm = m0 + mA + i * 16;           // row = b*S + s
            int s  = gm & (SS - 1);
            int ss = s + kw - 3;
            float v = 0.f;
            if ((unsigned)ss < (unsigned)SS)
                v = H[(long long)((gm & ~(SS - 1)) + ss) * CC + ci];
            As[kA][mA + i * 16] = v;
        }
        #pragma unroll
        for (int i = 0; i < 4; ++i) {
            int kk = (t >> 6) + i * 4, nn = t & 63;
            Bs[kk][nn] = W[(long long)(k0 + kk) * CC + (n0 + nn)];
        }
        __syncthreads();
        #pragma unroll
        for (int kk = 0; kk < KT; ++kk) {
            float4 a4 = *(const float4*)&As[kk][tr * 4];
            float4 b4 = *(const float4*)&Bs[kk][tc * 4];
            float ar[4] = {a4.x, a4.y, a4.z, a4.w};
            float br[4] = {b4.x, b4.y, b4.z, b4.w};
            #pragma unroll
            for (int i = 0; i < 4; ++i)
                #pragma unroll
                for (int j = 0; j < 4; ++j)
                    acc[i][j] += ar[i] * br[j];
        }
        __syncthreads();
    }

    float4 bb = *(const float4*)&bias[n0 + tc * 4];
    #pragma unroll
    for (int i = 0; i < 4; ++i) {
        int gm = m0 + tr * 4 + i;
        float4 rr = *(const float4*)&resid[(long long)gm * CC + n0 + tc * 4];
        float4 v;
        v.x = acc[i][0] + bb.x + rr.x;
        v.y = acc[i][1] + bb.y + rr.y;
        v.z = acc[i][2] + bb.z + rr.z;
        v.w = acc[i][3] + bb.w + rr.w;
        *(float4*)&C[(long long)gm * CC + n0 + tc * 4] = v;
    }
}

// ---------------------------------------------------------------------------
// out = x + position_encoding(s, c), computed inline.
// ---------------------------------------------------------------------------
__global__ __launch_bounds__(256)
void pe_add_kernel(const float* __restrict__ x, float* __restrict__ out, int n)
{
    int idx = blockIdx.x * 256 + threadIdx.x;
    if (idx >= n) return;
    int c = idx & (CC - 1);
    int s = (idx >> 8) & (SS - 1);
    int i = c >> 1;
    // freq = 10000^(2i/C) = exp2((2i/C) * log2(10000))
    float e = (2.0f * (float)i / (float)CC) * 13.28771237954945f;
    float freq = exp2f(e);
    float ang = (float)s / freq;
    float pe = (c & 1) ? cosf(ang) : sinf(ang);
    out[idx] = x[idx] + pe;
}

// ---------------------------------------------------------------------------
// LayerNorm over last dim C=256. One wave per row, 4 floats per lane.
// ---------------------------------------------------------------------------
__global__ __launch_bounds__(256)
void ln_kernel(const float* __restrict__ x, const float* __restrict__ g,
               const float* __restrict__ b, float* __restrict__ y)
{
    int wave = threadIdx.x >> 6;
    int lane = threadIdx.x & 63;
    long long row = (long long)blockIdx.x * 4 + wave;
    const float* xr = x + row * CC;
    float4 v = *(const float4*)&xr[lane * 4];

    float s = v.x + v.y + v.z + v.w;
    #pragma unroll
    for (int off = 32; off > 0; off >>= 1) s += __shfl_xor(s, off, 64);
    float m = s * (1.0f / CC);

    float4 d = make_float4(v.x - m, v.y - m, v.z - m, v.w - m);
    float sq = d.x * d.x + d.y * d.y + d.z * d.z + d.w * d.w;
    #pragma unroll
    for (int off = 32; off > 0; off >>= 1) sq += __shfl_xor(sq, off, 64);
    float rs = rsqrtf(sq * (1.0f / CC) + 1e-5f);

    float4 gg = *(const float4*)&g[lane * 4];
    float4 bv = *(const float4*)&b[lane * 4];
    float4 o;
    o.x = d.x * rs * gg.x + bv.x;
    o.y = d.y * rs * gg.y + bv.y;
    o.z = d.z * rs * gg.z + bv.z;
    o.w = d.w * rs * gg.w + bv.w;
    *(float4*)&y[row * CC + lane * 4] = o;
}

// ---------------------------------------------------------------------------
// Softmax over the BATCH axis (faithful to torch's implicit dim=0 on (B,S,T)):
// attn[b,s,t] = exp(sc[b,s,t] - max_b) / sum_b exp(...). In-place per head.
// One thread per (s,t); 32 batch values held in registers.
// ---------------------------------------------------------------------------
__global__ __launch_bounds__(256)
void softmax_batch_kernel(float* __restrict__ sc)
{
    int idx = blockIdx.x * 256 + threadIdx.x;   // idx over S*S
    float vals[BB];
    float mx = -3.4e38f;
    #pragma unroll
    for (int b = 0; b < BB; ++b) {
        vals[b] = sc[(long long)b * (SS * SS) + idx];
        mx = fmaxf(mx, vals[b]);
    }
    float sum = 0.f;
    #pragma unroll
    for (int b = 0; b < BB; ++b) {
        vals[b] = __expf(vals[b] - mx);
        sum += vals[b];
    }
    float inv = 1.0f / sum;
    #pragma unroll
    for (int b = 0; b < BB; ++b)
        sc[(long long)b * (SS * SS) + idx] = vals[b] * inv;
}

// ---------------------------------------------------------------------------
// Host-side launch helper
// ---------------------------------------------------------------------------
static void launch_gemm(hipStream_t stream, bool transB,
                        const float* A, const float* B, float* C,
                        int M, int N, int K, int lda, int ldb, int ldc,
                        long long sA, long long sB, long long sC, int batch,
                        const float* bias, const float* resid, long long sR, int ldr,
                        float alpha, int flags)
{
    dim3 grid(M / TILE, N / TILE, batch), block(256);
    if (transB)
        gemm_kernel<true><<<grid, block, 0, stream>>>(A, B, C, M, N, K, lda, ldb, ldc,
                                                      sA, sB, sC, bias, resid, sR, ldr,
                                                      alpha, flags);
    else
        gemm_kernel<false><<<grid, block, 0, stream>>>(A, B, C, M, N, K, lda, ldb, ldc,
                                                       sA, sB, sC, bias, resid, sR, ldr,
                                                       alpha, flags);
}

extern "C" void kernel_launch(void* const* d_in, const int* in_sizes, int n_in,
                              void* d_out, int out_size, void* d_ws, size_t ws_size,
                              hipStream_t stream)
{
    const float* x      = (const float*)d_in[0];
    const float* conv_w = (const float*)d_in[1];   // (NC, KW, C, C)
    const float* conv_b = (const float*)d_in[2];   // (NC, C)
    const float* ln_g   = (const float*)d_in[3];
    const float* ln_b   = (const float*)d_in[4];
    const float* wq     = (const float*)d_in[5];   // (H, C, C)
    const float* wk     = (const float*)d_in[6];
    const float* wv     = (const float*)d_in[7];
    const float* w_proj = (const float*)d_in[8];   // (H*C, C)
    const float* ff_w   = (const float*)d_in[9];
    const float* ff_b   = (const float*)d_in[10];
    const float* ff2_w  = (const float*)d_in[11];
    const float* ff2_b  = (const float*)d_in[12];
    float* out = (float*)d_out;

    const long long T = (long long)BB * SS * CC;   // 4,194,304
    float* ws    = (float*)d_ws;
    float* bufA  = ws;            // ping
    float* bufH  = ws + T;        // LN output
    float* bufC  = ws + 2 * T;    // pong / per-head o / ff1
    float* bufQ  = ws + 3 * T;
    float* bufK  = ws + 4 * T;
    float* bufV  = ws + 5 * T;
    float* bufAc = ws + 6 * T;    // attention output accumulator
    float* bufS  = ws + 7 * T;    // scores (B,S,S) = 8,388,608 floats

    const int M = BB * SS;        // 16384
    const long long HSC = (long long)SS * CC;   // per-batch stride in q/k/v
    const long long SSS = (long long)SS * SS;   // per-batch stride in scores

    // 1) positional encoding
    pe_add_kernel<<<(int)((T + 255) / 256), 256, 0, stream>>>(x, bufA, (int)T);

    float* cur = bufA;
    float* alt = bufC;

    // 2) conv stack
    for (int k = 0; k < NCV; ++k) {
        ln_kernel<<<M / 4, 256, 0, stream>>>(cur, ln_g, ln_b, bufH);
        dim3 grid(M / TILE, CC / TILE, 1), block(256);
        conv_gemm_kernel<<<grid, block, 0, stream>>>(
            bufH, conv_w + (long long)k * KW * CC * CC, conv_b + k * CC, cur, alt);
        float* tmp = cur; cur = alt; alt = tmp;
    }

    // 3) attention
    ln_kernel<<<M / 4, 256, 0, stream>>>(cur, ln_g, ln_b, bufH);
    hipMemcpyAsync(bufAc, cur, T * sizeof(float), hipMemcpyDeviceToDevice, stream);

    for (int hh = 0; hh < NH; ++hh) {
        const float* wq_h = wq + (long long)hh * CC * CC;
        const float* wk_h = wk + (long long)hh * CC * CC;
        const float* wv_h = wv + (long long)hh * CC * CC;
        const float* wp_h = w_proj + (long long)hh * CC * CC;

        launch_gemm(stream, false, bufH, wq_h, bufQ, M, CC, CC, CC, CC, CC,
                    0, 0, 0, 1, nullptr, nullptr, 0, 0, 1.0f, 0);
        launch_gemm(stream, false, bufH, wk_h, bufK, M, CC, CC, CC, CC, CC,
                    0, 0, 0, 1, nullptr, nullptr, 0, 0, 0.0625f, 0);
        launch_gemm(stream, false, bufH, wv_h, bufV, M, CC, CC, CC, CC, CC,
                    0, 0, 0, 1, nullptr, nullptr, 0, 0, 1.0f, 0);

        // scores[b] = q[b] @ k[b]^T   (512x512x256, batch=32)
        launch_gemm(stream, true, bufQ, bufK, bufS, SS, SS, CC, CC, CC, SS,
                    HSC, HSC, SSS, BB, nullptr, nullptr, 0, 0, 1.0f, 0);

        // softmax over batch axis, in place
        softmax_batch_kernel<<<(SS * SS) / 256, 256, 0, stream>>>(bufS);

        // o[b] = attn[b] @ v[b]   (512x256x512, batch=32) -> alt (B,S,C)
        launch_gemm(stream, false, bufS, bufV, alt, SS, CC, SS, SS, CC, CC,
                    SSS, HSC, HSC, BB, nullptr, nullptr, 0, 0, 1.0f, 0);

        // acc += o @ w_proj[h]
        launch_gemm(stream, false, alt, wp_h, bufAc, M, CC, CC, CC, CC, CC,
                    0, 0, 0, 1, nullptr, nullptr, 0, 0, 1.0f, 2);
    }
    cur = bufAc;   // attention output (residual already seeded)

    // 4) feed-forward
    ln_kernel<<<M / 4, 256, 0, stream>>>(cur, ln_g, ln_b, bufH);
    launch_gemm(stream, false, bufH, ff_w, bufC, M, CC, CC, CC, CC, CC,
                0, 0, 0, 1, ff_b, nullptr, 0, 0, 1.0f, 1);          // relu(h@W+b)
    launch_gemm(stream, false, bufC, ff2_w, out, M, CC, CC, CC, CC, CC,
                0, 0, 0, 1, ff2_b, cur, 0, CC, 1.0f, 0);            // + bias + resid
}

// Round 6
// 1165.949 us; speedup vs baseline: 3.0513x; 3.0513x over previous
//
#include <hip/hip_runtime.h>

// Problem constants (B=32, S=512, C=256, H=8, NC=4, KW=7)
#define BB 32
#define SS 512
#define CC 256
#define NH 8
#define NCV 4

using s8v   = __attribute__((ext_vector_type(8))) short;   // 8 bf16 raw (4 VGPR)
using f32x4 = __attribute__((ext_vector_type(4))) float;

__device__ __forceinline__ unsigned short f2bf(float f) {
    union { float f; unsigned int u; } v; v.f = f;
    unsigned int r = (v.u + 0x7fffu + ((v.u >> 16) & 1u)) >> 16;   // RNE
    return (unsigned short)r;
}

// ---------------------------------------------------------------------------
// MFMA GEMM (TN): C[m][n] = sum_k A[m][k] * B[n][k]   (A row-major MxK bf16,
// B n-major NxK bf16).  128x128 tile, BK=32, 4 waves x (64x64), 2-phase
// reg-staged prefetch.  M,N divisible by 128, K by 32.
// flags: 1=OUT_BF16, 2=RELU, 4=ACCUM(f32 C += )
// ---------------------------------------------------------------------------
#define F_OUT16 1
#define F_RELU  2
#define F_ACCUM 4

__global__ __launch_bounds__(256)
void gemm_mfma(const unsigned short* __restrict__ A, int lda, long long sA,
               const unsigned short* __restrict__ B, int ldb, long long sB,
               void* __restrict__ Cp, int ldc, long long sC,
               int K,
               const float* __restrict__ bias,
               const float* __restrict__ resid,
               float alpha, int flags)
{
    __shared__ unsigned short As[128][32];
    __shared__ unsigned short Bs[128][32];
    const int bz = blockIdx.z;
    A += bz * sA;  B += bz * sB;
    float*          Cf  = (float*)Cp + bz * sC;
    unsigned short* C16 = (unsigned short*)Cp + bz * sC;
    const float*    Rp  = resid ? resid + bz * sC : nullptr;

    const int m0 = blockIdx.x * 128, n0 = blockIdx.y * 128;
    const int t = threadIdx.x;
    const int w = t >> 6, lane = t & 63;
    const int wr = (w >> 1) * 64, wc = (w & 1) * 64;
    const int lr = lane & 15, lg = lane >> 4;

    // staging: thread -> (row, 16B slot); two passes cover 128 rows
    const int srow = t >> 2, sslot = t & 3;
    const unsigned short* Ag0 = A + (size_t)(m0 + srow) * lda + sslot * 8;
    const unsigned short* Ag1 = Ag0 + (size_t)64 * lda;
    const unsigned short* Bg0 = B + (size_t)(n0 + srow) * ldb + sslot * 8;
    const unsigned short* Bg1 = Bg0 + (size_t)64 * ldb;

    f32x4 acc[4][4] = {};

    const int nt = K / 32;
    uint4 ra0 = *(const uint4*)(Ag0);
    uint4 ra1 = *(const uint4*)(Ag1);
    uint4 rb0 = *(const uint4*)(Bg0);
    uint4 rb1 = *(const uint4*)(Bg1);
    *(uint4*)&As[srow][sslot * 8]      = ra0;
    *(uint4*)&As[srow + 64][sslot * 8] = ra1;
    *(uint4*)&Bs[srow][sslot * 8]      = rb0;
    *(uint4*)&Bs[srow + 64][sslot * 8] = rb1;
    __syncthreads();

    for (int tk = 0; tk < nt; ++tk) {
        const bool more = (tk + 1 < nt);
        if (more) {
            int ko = (tk + 1) * 32;                 // element offset
            ra0 = *(const uint4*)(Ag0 + ko);
            ra1 = *(const uint4*)(Ag1 + ko);
            rb0 = *(const uint4*)(Bg0 + ko);
            rb1 = *(const uint4*)(Bg1 + ko);
        }
        s8v af[4], bf[4];
        #pragma unroll
        for (int mi = 0; mi < 4; ++mi)
            af[mi] = *(const s8v*)&As[wr + mi * 16 + lr][lg * 8];
        #pragma unroll
        for (int ni = 0; ni < 4; ++ni)
            bf[ni] = *(const s8v*)&Bs[wc + ni * 16 + lr][lg * 8];
        #pragma unroll
        for (int mi = 0; mi < 4; ++mi)
            #pragma unroll
            for (int ni = 0; ni < 4; ++ni)
                acc[mi][ni] = __builtin_amdgcn_mfma_f32_16x16x32_bf16(
                    af[mi], bf[ni], acc[mi][ni], 0, 0, 0);
        __syncthreads();
        if (more) {
            *(uint4*)&As[srow][sslot * 8]      = ra0;
            *(uint4*)&As[srow + 64][sslot * 8] = ra1;
            *(uint4*)&Bs[srow][sslot * 8]      = rb0;
            *(uint4*)&Bs[srow + 64][sslot * 8] = rb1;
            __syncthreads();
        }
    }

    float bv[4] = {0.f, 0.f, 0.f, 0.f};
    if (bias) {
        #pragma unroll
        for (int ni = 0; ni < 4; ++ni) bv[ni] = bias[n0 + wc + ni * 16 + lr];
    }
    #pragma unroll
    for (int mi = 0; mi < 4; ++mi) {
        #pragma unroll
        for (int j = 0; j < 4; ++j) {
            size_t ro = (size_t)(m0 + wr + mi * 16 + lg * 4 + j) * ldc;
            #pragma unroll
            for (int ni = 0; ni < 4; ++ni) {
                int gc = n0 + wc + ni * 16 + lr;
                float v = acc[mi][ni][j] * alpha + bv[ni];
                if (flags & F_RELU) v = fmaxf(v, 0.f);
                if (Rp) v += Rp[ro + gc];
                if (flags & F_ACCUM) v += Cf[ro + gc];
                if (flags & F_OUT16) C16[ro + gc] = f2bf(v);
                else                 Cf[ro + gc] = v;
            }
        }
    }
}

// ---------------------------------------------------------------------------
// Conv1d(k=7, same pad) as gather-A MFMA GEMM.
// A[m][k] with m=b*S+s, k=kw*C+ci  ->  h16[b, s+kw-3, ci] (0 outside).
// B = convT (C x KW*C, n-major bf16).  Out f32 = acc + bias + resid.
// ---------------------------------------------------------------------------
__global__ __launch_bounds__(256)
void conv_mfma(const unsigned short* __restrict__ h16,
               const unsigned short* __restrict__ Bw,
               const float* __restrict__ bias,
               const float* __restrict__ resid,
               float* __restrict__ C)
{
    __shared__ unsigned short As[128][32];
    __shared__ unsigned short Bs[128][32];
    const int m0 = blockIdx.x * 128, n0 = blockIdx.y * 128;
    const int t = threadIdx.x;
    const int w = t >> 6, lane = t & 63;
    const int wr = (w >> 1) * 64, wc = (w & 1) * 64;
    const int lr = lane & 15, lg = lane >> 4;

    const int srow = t >> 2, sslot = t & 3;
    const int gm0 = m0 + srow;          // pass 0 row
    const int b0_ = gm0 >> 9, s0_ = gm0 & (SS - 1);
    const int gm1 = gm0 + 64;
    const int b1_ = gm1 >> 9, s1_ = gm1 & (SS - 1);
    const unsigned short* Bg0 = Bw + (size_t)(n0 + srow) * (7 * CC) + sslot * 8;
    const unsigned short* Bg1 = Bg0 + (size_t)64 * (7 * CC);

    f32x4 acc[4][4] = {};
    const int nt = (7 * CC) / 32;       // 56

    uint4 ra0, ra1, rb0, rb1;
    {
        int kg = sslot * 8;
        int kw = kg >> 8, ci = kg & (CC - 1);
        int ss0 = s0_ + kw - 3, ss1 = s1_ + kw - 3;
        ra0 = make_uint4(0,0,0,0); ra1 = make_uint4(0,0,0,0);
        if ((unsigned)ss0 < (unsigned)SS)
            ra0 = *(const uint4*)&h16[((size_t)(b0_ * SS + ss0)) * CC + ci];
        if ((unsigned)ss1 < (unsigned)SS)
            ra1 = *(const uint4*)&h16[((size_t)(b1_ * SS + ss1)) * CC + ci];
        rb0 = *(const uint4*)(Bg0);
        rb1 = *(const uint4*)(Bg1);
    }
    *(uint4*)&As[srow][sslot * 8]      = ra0;
    *(uint4*)&As[srow + 64][sslot * 8] = ra1;
    *(uint4*)&Bs[srow][sslot * 8]      = rb0;
    *(uint4*)&Bs[srow + 64][sslot * 8] = rb1;
    __syncthreads();

    for (int tk = 0; tk < nt; ++tk) {
        const bool more = (tk + 1 < nt);
        if (more) {
            int kg = (tk + 1) * 32 + sslot * 8;
            int kw = kg >> 8, ci = kg & (CC - 1);
            int ss0 = s0_ + kw - 3, ss1 = s1_ + kw - 3;
            ra0 = make_uint4(0,0,0,0); ra1 = make_uint4(0,0,0,0);
            if ((unsigned)ss0 < (unsigned)SS)
                ra0 = *(const uint4*)&h16[((size_t)(b0_ * SS + ss0)) * CC + ci];
            if ((unsigned)ss1 < (unsigned)SS)
                ra1 = *(const uint4*)&h16[((size_t)(b1_ * SS + ss1)) * CC + ci];
            rb0 = *(const uint4*)(Bg0 + (tk + 1) * 32);
            rb1 = *(const uint4*)(Bg1 + (tk + 1) * 32);
        }
        s8v af[4], bf[4];
        #pragma unroll
        for (int mi = 0; mi < 4; ++mi)
            af[mi] = *(const s8v*)&As[wr + mi * 16 + lr][lg * 8];
        #pragma unroll
        for (int ni = 0; ni < 4; ++ni)
            bf[ni] = *(const s8v*)&Bs[wc + ni * 16 + lr][lg * 8];
        #pragma unroll
        for (int mi = 0; mi < 4; ++mi)
            #pragma unroll
            for (int ni = 0; ni < 4; ++ni)
                acc[mi][ni] = __builtin_amdgcn_mfma_f32_16x16x32_bf16(
                    af[mi], bf[ni], acc[mi][ni], 0, 0, 0);
        __syncthreads();
        if (more) {
            *(uint4*)&As[srow][sslot * 8]      = ra0;
            *(uint4*)&As[srow + 64][sslot * 8] = ra1;
            *(uint4*)&Bs[srow][sslot * 8]      = rb0;
            *(uint4*)&Bs[srow + 64][sslot * 8] = rb1;
            __syncthreads();
        }
    }

    float bv[4];
    #pragma unroll
    for (int ni = 0; ni < 4; ++ni) bv[ni] = bias[n0 + wc + ni * 16 + lr];
    #pragma unroll
    for (int mi = 0; mi < 4; ++mi) {
        #pragma unroll
        for (int j = 0; j < 4; ++j) {
            size_t ro = (size_t)(m0 + wr + mi * 16 + lg * 4 + j) * CC;
            #pragma unroll
            for (int ni = 0; ni < 4; ++ni) {
                int gc = n0 + wc + ni * 16 + lr;
                C[ro + gc] = acc[mi][ni][j] + bv[ni] + resid[ro + gc];
            }
        }
    }
}

// ---------------------------------------------------------------------------
// Cast+transpose: src f32 (R x Cn) -> dst bf16 (Cn x R), batched over z.
// ---------------------------------------------------------------------------
__global__ __launch_bounds__(256)
void ct_kernel(const float* __restrict__ src, unsigned short* __restrict__ dst,
               int R, int Cn)
{
    __shared__ unsigned short tile[32][36];
    const size_t zoff = (size_t)blockIdx.z * R * Cn;
    src += zoff;  dst += zoff;
    const int r0 = blockIdx.x * 32, c0 = blockIdx.y * 32;
    const int t = threadIdx.x;
    const int r = t >> 3, c4 = (t & 7) * 4;
    float4 f = *(const float4*)&src[(size_t)(r0 + r) * Cn + c0 + c4];
    tile[r][c4 + 0] = f2bf(f.x);
    tile[r][c4 + 1] = f2bf(f.y);
    tile[r][c4 + 2] = f2bf(f.z);
    tile[r][c4 + 3] = f2bf(f.w);
    __syncthreads();
    ushort4 o;
    o.x = tile[c4 + 0][r];
    o.y = tile[c4 + 1][r];
    o.z = tile[c4 + 2][r];
    o.w = tile[c4 + 3][r];
    *(ushort4*)&dst[(size_t)(c0 + r) * R + r0 + c4] = o;
}

// ---------------------------------------------------------------------------
// out = x + position_encoding(s, c)   (f32)
// ---------------------------------------------------------------------------
__global__ __launch_bounds__(256)
void pe_add_kernel(const float* __restrict__ x, float* __restrict__ out, int n)
{
    int idx = blockIdx.x * 256 + threadIdx.x;
    if (idx >= n) return;
    int c = idx & (CC - 1);
    int s = (idx >> 8) & (SS - 1);
    int i = c >> 1;
    float e = (2.0f * (float)i / (float)CC) * 13.28771237954945f;  // log2(10000)
    float freq = exp2f(e);
    float ang = (float)s / freq;
    float pe = (c & 1) ? cosf(ang) : sinf(ang);
    out[idx] = x[idx] + pe;
}

// ---------------------------------------------------------------------------
// LayerNorm f32 in -> bf16 out. One wave per row (C=256), 4 floats/lane.
// ---------------------------------------------------------------------------
__global__ __launch_bounds__(256)
void ln16_kernel(const float* __restrict__ x, const float* __restrict__ g,
                 const float* __restrict__ b, unsigned short* __restrict__ y)
{
    int wave = threadIdx.x >> 6, lane = threadIdx.x & 63;
    size_t row = (size_t)blockIdx.x * 4 + wave;
    const float* xr = x + row * CC;
    float4 v = *(const float4*)&xr[lane * 4];

    float s = v.x + v.y + v.z + v.w;
    #pragma unroll
    for (int off = 32; off > 0; off >>= 1) s += __shfl_xor(s, off, 64);
    float m = s * (1.0f / CC);

    float4 d = make_float4(v.x - m, v.y - m, v.z - m, v.w - m);
    float sq = d.x * d.x + d.y * d.y + d.z * d.z + d.w * d.w;
    #pragma unroll
    for (int off = 32; off > 0; off >>= 1) sq += __shfl_xor(sq, off, 64);
    float rs = rsqrtf(sq * (1.0f / CC) + 1e-5f);

    float4 gg = *(const float4*)&g[lane * 4];
    float4 bv = *(const float4*)&b[lane * 4];
    ushort4 o;
    o.x = f2bf(d.x * rs * gg.x + bv.x);
    o.y = f2bf(d.y * rs * gg.y + bv.y);
    o.z = f2bf(d.z * rs * gg.z + bv.z);
    o.w = f2bf(d.w * rs * gg.w + bv.w);
    *(ushort4*)&y[row * CC + lane * 4] = o;
}

// ---------------------------------------------------------------------------
// Softmax over the BATCH axis; reads f32 scores (B,S,T), writes bf16 attn.
// ---------------------------------------------------------------------------
__global__ __launch_bounds__(256)
void softmax16_kernel(const float* __restrict__ sc, unsigned short* __restrict__ at)
{
    int idx = blockIdx.x * 256 + threadIdx.x;   // over S*T
    float vals[BB];
    float mx = -3.4e38f;
    #pragma unroll
    for (int b = 0; b < BB; ++b) {
        vals[b] = sc[(size_t)b * (SS * SS) + idx];
        mx = fmaxf(mx, vals[b]);
    }
    float sum = 0.f;
    #pragma unroll
    for (int b = 0; b < BB; ++b) {
        vals[b] = __expf(vals[b] - mx);
        sum += vals[b];
    }
    float inv = 1.0f / sum;
    #pragma unroll
    for (int b = 0; b < BB; ++b)
        at[(size_t)b * (SS * SS) + idx] = f2bf(vals[b] * inv);
}

// ---------------------------------------------------------------------------
extern "C" void kernel_launch(void* const* d_in, const int* in_sizes, int n_in,
                              void* d_out, int out_size, void* d_ws, size_t ws_size,
                              hipStream_t stream)
{
    const float* x      = (const float*)d_in[0];
    const float* conv_w = (const float*)d_in[1];   // (NC, KW, C, C) = (NC, KW*C, C)
    const float* conv_b = (const float*)d_in[2];   // (NC, C)
    const float* ln_g   = (const float*)d_in[3];
    const float* ln_b   = (const float*)d_in[4];
    const float* wq     = (const float*)d_in[5];   // (H, C, C)
    const float* wk     = (const float*)d_in[6];
    const float* wv     = (const float*)d_in[7];
    const float* w_proj = (const float*)d_in[8];   // (H*C, C)
    const float* ff_w   = (const float*)d_in[9];
    const float* ff_b   = (const float*)d_in[10];
    const float* ff2_w  = (const float*)d_in[11];
    const float* ff2_b  = (const float*)d_in[12];
    float* out = (float*)d_out;

    char* W = (char*)d_ws;
    float*          bufA    = (float*)(W);                       // 16 MB f32 residual
    float*          bufC    = (float*)(W + (16u << 20));         // 16 MB f32 residual/acc
    float*          scoresF = (float*)(W + (32u << 20));         // 32 MB f32 scores
    unsigned short* attn16  = (unsigned short*)(W + (64u << 20)); // 16 MB
    unsigned short* h16     = (unsigned short*)(W + (80u << 20)); //  8 MB
    unsigned short* q16     = (unsigned short*)(W + (88u << 20));
    unsigned short* k16     = (unsigned short*)(W + (96u << 20));
    unsigned short* vT16    = (unsigned short*)(W + (104u << 20));
    unsigned short* o16     = (unsigned short*)(W + (112u << 20));
    unsigned short* ff16    = (unsigned short*)(W + (120u << 20));
    unsigned short* convT   = (unsigned short*)(W + (128u << 20));
    unsigned short* wqT  = convT + (size_t)NCV * (7 * CC) * CC;   // 4*1792*256
    unsigned short* wkT  = wqT  + (size_t)NH * CC * CC;
    unsigned short* wvT  = wkT  + (size_t)NH * CC * CC;
    unsigned short* wpT  = wvT  + (size_t)NH * CC * CC;           // (256 x 2048)
    unsigned short* ffT  = wpT  + (size_t)(NH * CC) * CC;
    unsigned short* ff2T = ffT  + (size_t)CC * CC;

    const int M = BB * SS;                     // 16384
    const long long BSC = (long long)SS * CC;  // 131072 (per-batch activ stride)
    const long long SSS = (long long)SS * SS;  // 262144

    dim3 blk(256);

    // 0) weight cast+transpose (n-major bf16)
    ct_kernel<<<dim3((7 * CC) / 32, CC / 32, NCV), blk, 0, stream>>>(conv_w, convT, 7 * CC, CC);
    ct_kernel<<<dim3(CC / 32, CC / 32, NH), blk, 0, stream>>>(wq, wqT, CC, CC);
    ct_kernel<<<dim3(CC / 32, CC / 32, NH), blk, 0, stream>>>(wk, wkT, CC, CC);
    ct_kernel<<<dim3(CC / 32, CC / 32, NH), blk, 0, stream>>>(wv, wvT, CC, CC);
    ct_kernel<<<dim3((NH * CC) / 32, CC / 32, 1), blk, 0, stream>>>(w_proj, wpT, NH * CC, CC);
    ct_kernel<<<dim3(CC / 32, CC / 32, 1), blk, 0, stream>>>(ff_w, ffT, CC, CC);
    ct_kernel<<<dim3(CC / 32, CC / 32, 1), blk, 0, stream>>>(ff2_w, ff2T, CC, CC);

    // 1) positional encoding
    const int T = M * CC;
    pe_add_kernel<<<T / 256, blk, 0, stream>>>(x, bufA, T);

    // 2) conv stack (residual stream f32 ping-pongs bufA <-> bufC)
    float* cur = bufA;
    float* alt = bufC;
    for (int k = 0; k < NCV; ++k) {
        ln16_kernel<<<M / 4, blk, 0, stream>>>(cur, ln_g, ln_b, h16);
        conv_mfma<<<dim3(M / 128, CC / 128), blk, 0, stream>>>(
            h16, convT + (size_t)k * (7 * CC) * CC, conv_b + k * CC, cur, alt);
        float* tmp = cur; cur = alt; alt = tmp;
    }
    // after 4 convs: cur == bufA, alt == bufC

    // 3) attention
    ln16_kernel<<<M / 4, blk, 0, stream>>>(bufA, ln_g, ln_b, h16);
    hipMemcpyAsync(bufC, bufA, (size_t)T * sizeof(float),
                   hipMemcpyDeviceToDevice, stream);   // residual seed for accumulation

    for (int hh = 0; hh < NH; ++hh) {
        const unsigned short* wqTh = wqT + (size_t)hh * CC * CC;
        const unsigned short* wkTh = wkT + (size_t)hh * CC * CC;
        const unsigned short* wvTh = wvT + (size_t)hh * CC * CC;

        // q = h @ wq_h   (16384 x 256, K=256) -> bf16
        gemm_mfma<<<dim3(M / 128, CC / 128, 1), blk, 0, stream>>>(
            h16, CC, 0, wqTh, CC, 0, q16, CC, 0, CC,
            nullptr, nullptr, 1.0f, F_OUT16);
        // k = h @ wk_h (unscaled; 1/16 folded into scores alpha)
        gemm_mfma<<<dim3(M / 128, CC / 128, 1), blk, 0, stream>>>(
            h16, CC, 0, wkTh, CC, 0, k16, CC, 0, CC,
            nullptr, nullptr, 1.0f, F_OUT16);
        // vT[b] = wv_h^T @ h[b]^T  -> (C x S) per batch, bf16
        gemm_mfma<<<dim3(CC / 128, SS / 128, BB), blk, 0, stream>>>(
            wvTh, CC, 0, h16, CC, BSC, vT16, SS, BSC, CC,
            nullptr, nullptr, 1.0f, F_OUT16);
        // scores[b] = (q[b] @ k[b]^T) / 16  -> f32
        gemm_mfma<<<dim3(SS / 128, SS / 128, BB), blk, 0, stream>>>(
            q16, CC, BSC, k16, CC, BSC, scoresF, SS, SSS, CC,
            nullptr, nullptr, 0.0625f, 0);
        // softmax over batch axis -> bf16 attn
        softmax16_kernel<<<(SS * SS) / 256, blk, 0, stream>>>(scoresF, attn16);
        // o[b] = attn[b] @ v[b]  (A=attn SxT, B=vT CxT n-major) -> bf16
        gemm_mfma<<<dim3(SS / 128, CC / 128, BB), blk, 0, stream>>>(
            attn16, SS, SSS, vT16, SS, BSC, o16, CC, BSC, SS,
            nullptr, nullptr, 1.0f, F_OUT16);
        // bufC += o @ w_proj[h]
        gemm_mfma<<<dim3(M / 128, CC / 128, 1), blk, 0, stream>>>(
            o16, CC, 0, wpT + (size_t)hh * CC, NH * CC, 0, bufC, CC, 0, CC,
            nullptr, nullptr, 1.0f, F_ACCUM);
    }

    // 4) feed-forward (residual = bufC)
    ln16_kernel<<<M / 4, blk, 0, stream>>>(bufC, ln_g, ln_b, h16);
    gemm_mfma<<<dim3(M / 128, CC / 128, 1), blk, 0, stream>>>(
        h16, CC, 0, ffT, CC, 0, ff16, CC, 0, CC,
        ff_b, nullptr, 1.0f, F_OUT16 | F_RELU);
    gemm_mfma<<<dim3(M / 128, CC / 128, 1), blk, 0, stream>>>(
        ff16, CC, 0, ff2T, CC, 0, out, CC, 0, CC,
        ff2_b, bufC, 1.0f, 0);
}

// Round 7
// 879.249 us; speedup vs baseline: 4.0463x; 1.3261x over previous
//
#include <hip/hip_runtime.h>

// Problem constants (B=32, S=512, C=256, H=8, NC=4, KW=7)
#define BB 32
#define SS 512
#define CC 256
#define NH 8
#define NCV 4
#define SSS_ (SS * SS)          // 262144

using s8v   = __attribute__((ext_vector_type(8))) short;   // 8 bf16 raw (4 VGPR)
using f32x4 = __attribute__((ext_vector_type(4))) float;

__device__ __forceinline__ unsigned short f2bf(float f) {
    union { float f; unsigned int u; } v; v.f = f;
    unsigned int r = (v.u + 0x7fffu + ((v.u >> 16) & 1u)) >> 16;   // RNE
    return (unsigned short)r;
}
__device__ __forceinline__ float bf2f(unsigned short u) {
    union { unsigned int u; float f; } v; v.u = ((unsigned int)u) << 16;
    return v.f;
}

// ---------------------------------------------------------------------------
// MFMA GEMM (TN): C[m][n] = sum_k A[m][k]*B[n][k].  A row-major MxK bf16,
// B n-major NxK bf16.  128x128 tile, BK=32, 4 waves x (64x64), reg prefetch.
// Generalized z-offsets: zlo = bz & zmask, zhi = bz >> zshift;
//   off_X = zhi*sX2 + zlo*sX1   (use zmask=0/zshift=0 for plain batching).
// flags: 1=OUT_BF16, 2=RELU, 4=ACCUM(f32 C+=)
// ---------------------------------------------------------------------------
#define F_OUT16 1
#define F_RELU  2
#define F_ACCUM 4

__global__ __launch_bounds__(256)
void gemm_mfma(const unsigned short* __restrict__ A, int lda, long long sA1, long long sA2,
               const unsigned short* __restrict__ B, int ldb, long long sB1, long long sB2,
               void* __restrict__ Cp, int ldc, long long sC1, long long sC2,
               int K, int zshift, int zmask,
               const float* __restrict__ bias,
               const float* __restrict__ resid,
               float alpha, int flags)
{
    __shared__ unsigned short As[128][32];
    __shared__ unsigned short Bs[128][32];
    const int bz = blockIdx.z;
    const long long zlo = bz & zmask, zhi = bz >> zshift;
    A += zhi * sA2 + zlo * sA1;
    B += zhi * sB2 + zlo * sB1;
    const long long coff = zhi * sC2 + zlo * sC1;
    float*          Cf  = (float*)Cp + coff;
    unsigned short* C16 = (unsigned short*)Cp + coff;
    const float*    Rp  = resid ? resid + coff : nullptr;

    const int m0 = blockIdx.x * 128, n0 = blockIdx.y * 128;
    const int t = threadIdx.x;
    const int w = t >> 6, lane = t & 63;
    const int wr = (w >> 1) * 64, wc = (w & 1) * 64;
    const int lr = lane & 15, lg = lane >> 4;

    const int srow = t >> 2, sslot = t & 3;
    const unsigned short* Ag0 = A + (size_t)(m0 + srow) * lda + sslot * 8;
    const unsigned short* Ag1 = Ag0 + (size_t)64 * lda;
    const unsigned short* Bg0 = B + (size_t)(n0 + srow) * ldb + sslot * 8;
    const unsigned short* Bg1 = Bg0 + (size_t)64 * ldb;

    f32x4 acc[4][4] = {};

    const int nt = K / 32;
    uint4 ra0 = *(const uint4*)(Ag0);
    uint4 ra1 = *(const uint4*)(Ag1);
    uint4 rb0 = *(const uint4*)(Bg0);
    uint4 rb1 = *(const uint4*)(Bg1);
    *(uint4*)&As[srow][sslot * 8]      = ra0;
    *(uint4*)&As[srow + 64][sslot * 8] = ra1;
    *(uint4*)&Bs[srow][sslot * 8]      = rb0;
    *(uint4*)&Bs[srow + 64][sslot * 8] = rb1;
    __syncthreads();

    for (int tk = 0; tk < nt; ++tk) {
        const bool more = (tk + 1 < nt);
        if (more) {
            int ko = (tk + 1) * 32;
            ra0 = *(const uint4*)(Ag0 + ko);
            ra1 = *(const uint4*)(Ag1 + ko);
            rb0 = *(const uint4*)(Bg0 + ko);
            rb1 = *(const uint4*)(Bg1 + ko);
        }
        s8v af[4], bf[4];
        #pragma unroll
        for (int mi = 0; mi < 4; ++mi)
            af[mi] = *(const s8v*)&As[wr + mi * 16 + lr][lg * 8];
        #pragma unroll
        for (int ni = 0; ni < 4; ++ni)
            bf[ni] = *(const s8v*)&Bs[wc + ni * 16 + lr][lg * 8];
        #pragma unroll
        for (int mi = 0; mi < 4; ++mi)
            #pragma unroll
            for (int ni = 0; ni < 4; ++ni)
                acc[mi][ni] = __builtin_amdgcn_mfma_f32_16x16x32_bf16(
                    af[mi], bf[ni], acc[mi][ni], 0, 0, 0);
        __syncthreads();
        if (more) {
            *(uint4*)&As[srow][sslot * 8]      = ra0;
            *(uint4*)&As[srow + 64][sslot * 8] = ra1;
            *(uint4*)&Bs[srow][sslot * 8]      = rb0;
            *(uint4*)&Bs[srow + 64][sslot * 8] = rb1;
            __syncthreads();
        }
    }

    float bv[4] = {0.f, 0.f, 0.f, 0.f};
    if (bias) {
        #pragma unroll
        for (int ni = 0; ni < 4; ++ni) bv[ni] = bias[n0 + wc + ni * 16 + lr];
    }
    #pragma unroll
    for (int mi = 0; mi < 4; ++mi) {
        #pragma unroll
        for (int j = 0; j < 4; ++j) {
            size_t ro = (size_t)(m0 + wr + mi * 16 + lg * 4 + j) * ldc;
            #pragma unroll
            for (int ni = 0; ni < 4; ++ni) {
                int gc = n0 + wc + ni * 16 + lr;
                float v = acc[mi][ni][j] * alpha + bv[ni];
                if (flags & F_RELU) v = fmaxf(v, 0.f);
                if (Rp) v += Rp[ro + gc];
                if (flags & F_ACCUM) v += Cf[ro + gc];
                if (flags & F_OUT16) C16[ro + gc] = f2bf(v);
                else                 Cf[ro + gc] = v;
            }
        }
    }
}

// ---------------------------------------------------------------------------
// Conv1d(k=7, same pad) as gather-A MFMA GEMM (unchanged from R6 kernel).
// ---------------------------------------------------------------------------
__global__ __launch_bounds__(256)
void conv_mfma(const unsigned short* __restrict__ h16,
               const unsigned short* __restrict__ Bw,
               const float* __restrict__ bias,
               const float* __restrict__ resid,
               float* __restrict__ C)
{
    __shared__ unsigned short As[128][32];
    __shared__ unsigned short Bs[128][32];
    const int m0 = blockIdx.x * 128, n0 = blockIdx.y * 128;
    const int t = threadIdx.x;
    const int w = t >> 6, lane = t & 63;
    const int wr = (w >> 1) * 64, wc = (w & 1) * 64;
    const int lr = lane & 15, lg = lane >> 4;

    const int srow = t >> 2, sslot = t & 3;
    const int gm0 = m0 + srow;
    const int b0_ = gm0 >> 9, s0_ = gm0 & (SS - 1);
    const int gm1 = gm0 + 64;
    const int b1_ = gm1 >> 9, s1_ = gm1 & (SS - 1);
    const unsigned short* Bg0 = Bw + (size_t)(n0 + srow) * (7 * CC) + sslot * 8;
    const unsigned short* Bg1 = Bg0 + (size_t)64 * (7 * CC);

    f32x4 acc[4][4] = {};
    const int nt = (7 * CC) / 32;       // 56

    uint4 ra0, ra1, rb0, rb1;
    {
        int kg = sslot * 8;
        int kw = kg >> 8, ci = kg & (CC - 1);
        int ss0 = s0_ + kw - 3, ss1 = s1_ + kw - 3;
        ra0 = make_uint4(0,0,0,0); ra1 = make_uint4(0,0,0,0);
        if ((unsigned)ss0 < (unsigned)SS)
            ra0 = *(const uint4*)&h16[((size_t)(b0_ * SS + ss0)) * CC + ci];
        if ((unsigned)ss1 < (unsigned)SS)
            ra1 = *(const uint4*)&h16[((size_t)(b1_ * SS + ss1)) * CC + ci];
        rb0 = *(const uint4*)(Bg0);
        rb1 = *(const uint4*)(Bg1);
    }
    *(uint4*)&As[srow][sslot * 8]      = ra0;
    *(uint4*)&As[srow + 64][sslot * 8] = ra1;
    *(uint4*)&Bs[srow][sslot * 8]      = rb0;
    *(uint4*)&Bs[srow + 64][sslot * 8] = rb1;
    __syncthreads();

    for (int tk = 0; tk < nt; ++tk) {
        const bool more = (tk + 1 < nt);
        if (more) {
            int kg = (tk + 1) * 32 + sslot * 8;
            int kw = kg >> 8, ci = kg & (CC - 1);
            int ss0 = s0_ + kw - 3, ss1 = s1_ + kw - 3;
            ra0 = make_uint4(0,0,0,0); ra1 = make_uint4(0,0,0,0);
            if ((unsigned)ss0 < (unsigned)SS)
                ra0 = *(const uint4*)&h16[((size_t)(b0_ * SS + ss0)) * CC + ci];
            if ((unsigned)ss1 < (unsigned)SS)
                ra1 = *(const uint4*)&h16[((size_t)(b1_ * SS + ss1)) * CC + ci];
            rb0 = *(const uint4*)(Bg0 + (tk + 1) * 32);
            rb1 = *(const uint4*)(Bg1 + (tk + 1) * 32);
        }
        s8v af[4], bf[4];
        #pragma unroll
        for (int mi = 0; mi < 4; ++mi)
            af[mi] = *(const s8v*)&As[wr + mi * 16 + lr][lg * 8];
        #pragma unroll
        for (int ni = 0; ni < 4; ++ni)
            bf[ni] = *(const s8v*)&Bs[wc + ni * 16 + lr][lg * 8];
        #pragma unroll
        for (int mi = 0; mi < 4; ++mi)
            #pragma unroll
            for (int ni = 0; ni < 4; ++ni)
                acc[mi][ni] = __builtin_amdgcn_mfma_f32_16x16x32_bf16(
                    af[mi], bf[ni], acc[mi][ni], 0, 0, 0);
        __syncthreads();
        if (more) {
            *(uint4*)&As[srow][sslot * 8]      = ra0;
            *(uint4*)&As[srow + 64][sslot * 8] = ra1;
            *(uint4*)&Bs[srow][sslot * 8]      = rb0;
            *(uint4*)&Bs[srow + 64][sslot * 8] = rb1;
            __syncthreads();
        }
    }

    float bv[4];
    #pragma unroll
    for (int ni = 0; ni < 4; ++ni) bv[ni] = bias[n0 + wc + ni * 16 + lr];
    #pragma unroll
    for (int mi = 0; mi < 4; ++mi) {
        #pragma unroll
        for (int j = 0; j < 4; ++j) {
            size_t ro = (size_t)(m0 + wr + mi * 16 + lg * 4 + j) * CC;
            #pragma unroll
            for (int ni = 0; ni < 4; ++ni) {
                int gc = n0 + wc + ni * 16 + lr;
                C[ro + gc] = acc[mi][ni][j] + bv[ni] + resid[ro + gc];
            }
        }
    }
}

// ---------------------------------------------------------------------------
// Cast+transpose: src f32 (R x Cn) -> dst bf16 (Cn x R), batched over z.
// ---------------------------------------------------------------------------
__global__ __launch_bounds__(256)
void ct_kernel(const float* __restrict__ src, unsigned short* __restrict__ dst,
               int R, int Cn)
{
    __shared__ unsigned short tile[32][36];
    const size_t zoff = (size_t)blockIdx.z * R * Cn;
    src += zoff;  dst += zoff;
    const int r0 = blockIdx.x * 32, c0 = blockIdx.y * 32;
    const int t = threadIdx.x;
    const int r = t >> 3, c4 = (t & 7) * 4;
    float4 f = *(const float4*)&src[(size_t)(r0 + r) * Cn + c0 + c4];
    tile[r][c4 + 0] = f2bf(f.x);
    tile[r][c4 + 1] = f2bf(f.y);
    tile[r][c4 + 2] = f2bf(f.z);
    tile[r][c4 + 3] = f2bf(f.w);
    __syncthreads();
    ushort4 o;
    o.x = tile[c4 + 0][r];
    o.y = tile[c4 + 1][r];
    o.z = tile[c4 + 2][r];
    o.w = tile[c4 + 3][r];
    *(ushort4*)&dst[(size_t)(c0 + r) * R + r0 + c4] = o;
}

// ---------------------------------------------------------------------------
// Plain cast f32 -> bf16 for 3 equal-size weight arrays (wq, wk, wv).
// grid: (n/1024, 3); each thread converts 4 elements.
// ---------------------------------------------------------------------------
__global__ __launch_bounds__(256)
void cast3_kernel(const float* __restrict__ a0, const float* __restrict__ a1,
                  const float* __restrict__ a2,
                  unsigned short* __restrict__ o0, unsigned short* __restrict__ o1,
                  unsigned short* __restrict__ o2)
{
    const float* s = (blockIdx.y == 0) ? a0 : (blockIdx.y == 1) ? a1 : a2;
    unsigned short* d = (blockIdx.y == 0) ? o0 : (blockIdx.y == 1) ? o1 : o2;
    int i4 = (blockIdx.x * 256 + threadIdx.x) * 4;
    float4 f = *(const float4*)&s[i4];
    ushort4 o;
    o.x = f2bf(f.x); o.y = f2bf(f.y); o.z = f2bf(f.z); o.w = f2bf(f.w);
    *(ushort4*)&d[i4] = o;
}

// ---------------------------------------------------------------------------
// out = x + position_encoding(s, c)   (f32)
// ---------------------------------------------------------------------------
__global__ __launch_bounds__(256)
void pe_add_kernel(const float* __restrict__ x, float* __restrict__ out, int n)
{
    int idx = blockIdx.x * 256 + threadIdx.x;
    if (idx >= n) return;
    int c = idx & (CC - 1);
    int s = (idx >> 8) & (SS - 1);
    int i = c >> 1;
    float e = (2.0f * (float)i / (float)CC) * 13.28771237954945f;  // log2(10000)
    float freq = exp2f(e);
    float ang = (float)s / freq;
    float pe = (c & 1) ? cosf(ang) : sinf(ang);
    out[idx] = x[idx] + pe;
}

// ---------------------------------------------------------------------------
// LayerNorm f32 in -> bf16 out. One wave per row (C=256), 4 floats/lane.
// ---------------------------------------------------------------------------
__global__ __launch_bounds__(256)
void ln16_kernel(const float* __restrict__ x, const float* __restrict__ g,
                 const float* __restrict__ b, unsigned short* __restrict__ y)
{
    int wave = threadIdx.x >> 6, lane = threadIdx.x & 63;
    size_t row = (size_t)blockIdx.x * 4 + wave;
    const float* xr = x + row * CC;
    float4 v = *(const float4*)&xr[lane * 4];

    float s = v.x + v.y + v.z + v.w;
    #pragma unroll
    for (int off = 32; off > 0; off >>= 1) s += __shfl_xor(s, off, 64);
    float m = s * (1.0f / CC);

    float4 d = make_float4(v.x - m, v.y - m, v.z - m, v.w - m);
    float sq = d.x * d.x + d.y * d.y + d.z * d.z + d.w * d.w;
    #pragma unroll
    for (int off = 32; off > 0; off >>= 1) sq += __shfl_xor(sq, off, 64);
    float rs = rsqrtf(sq * (1.0f / CC) + 1e-5f);

    float4 gg = *(const float4*)&g[lane * 4];
    float4 bv = *(const float4*)&b[lane * 4];
    ushort4 o;
    o.x = f2bf(d.x * rs * gg.x + bv.x);
    o.y = f2bf(d.y * rs * gg.y + bv.y);
    o.z = f2bf(d.z * rs * gg.z + bv.z);
    o.w = f2bf(d.w * rs * gg.w + bv.w);
    *(ushort4*)&y[row * CC + lane * 4] = o;
}

// ---------------------------------------------------------------------------
// Softmax over the BATCH axis, 2 heads per launch, bf16 in-place.
// sc layout: (2, B, S, S) bf16.  idx over 2*S*S; vals[b] strided by S*S.
// ---------------------------------------------------------------------------
__global__ __launch_bounds__(256)
void softmax2_kernel(unsigned short* __restrict__ sc)
{
    int idx = blockIdx.x * 256 + threadIdx.x;            // over 2*SSS
    int g2 = idx >> 18;                                  // SSS = 2^18
    int st = idx & (SSS_ - 1);
    unsigned short* p = sc + (size_t)g2 * (32u * SSS_) + st;
    float vals[BB];
    float mx = -3.4e38f;
    #pragma unroll
    for (int b = 0; b < BB; ++b) {
        vals[b] = bf2f(p[(size_t)b * SSS_]);
        mx = fmaxf(mx, vals[b]);
    }
    float sum = 0.f;
    #pragma unroll
    for (int b = 0; b < BB; ++b) {
        vals[b] = __expf(vals[b] - mx);
        sum += vals[b];
    }
    float inv = 1.0f / sum;
    #pragma unroll
    for (int b = 0; b < BB; ++b)
        p[(size_t)b * SSS_] = f2bf(vals[b] * inv);
}

// ---------------------------------------------------------------------------
extern "C" void kernel_launch(void* const* d_in, const int* in_sizes, int n_in,
                              void* d_out, int out_size, void* d_ws, size_t ws_size,
                              hipStream_t stream)
{
    const float* x      = (const float*)d_in[0];
    const float* conv_w = (const float*)d_in[1];   // (NC, KW*C, C)
    const float* conv_b = (const float*)d_in[2];   // (NC, C)
    const float* ln_g   = (const float*)d_in[3];
    const float* ln_b   = (const float*)d_in[4];
    const float* wq     = (const float*)d_in[5];   // (H, C, C)
    const float* wk     = (const float*)d_in[6];
    const float* wv     = (const float*)d_in[7];
    const float* w_proj = (const float*)d_in[8];   // (H*C, C)
    const float* ff_w   = (const float*)d_in[9];
    const float* ff_b   = (const float*)d_in[10];
    const float* ff2_w  = (const float*)d_in[11];
    const float* ff2_b  = (const float*)d_in[12];
    float* out = (float*)d_out;

    // -------- workspace layout (peak exactly 144 MiB, proven available) ----
    char* W = (char*)d_ws;
    // transient precompute region (dead before pe_add writes bufA):
    unsigned short* wq16 = (unsigned short*)(W + (0u  << 20));   // 1 MiB
    unsigned short* wk16 = (unsigned short*)(W + (1u  << 20));   // 1 MiB
    unsigned short* wv16 = (unsigned short*)(W + (2u  << 20));   // 1 MiB
    unsigned short* wpT  = (unsigned short*)(W + (3u  << 20));   // 1 MiB
    // residual stream + attention buffers:
    float*          bufA = (float*)(W + (0u  << 20));            // 16 MiB (conv ping)
    unsigned short* sc16 = (unsigned short*)(W + (0u  << 20));   // 32 MiB (overlays bufA after it dies)
    float*          bufC = (float*)(W + (32u << 20));            // 16 MiB (conv pong / attn out)
    unsigned short* h16  = (unsigned short*)(W + (48u << 20));   //  8 MiB
    unsigned short* qm16 = (unsigned short*)(W + (56u << 20));   // 64 MiB (H,B,S,C)
    unsigned short* ff16 = (unsigned short*)(W + (56u << 20));   //  8 MiB (reuse, post-attn)
    unsigned short* zT16 = (unsigned short*)(W + (120u << 20));  // 16 MiB (2,B,C,S)
    // persistent weights:
    unsigned short* convT = (unsigned short*)(W + (136u << 20)); // 3.5 MiB
    unsigned short* ffT   = (unsigned short*)(W + (140u << 20)); // 128 KiB
    unsigned short* ff2T  = (unsigned short*)(W + (141u << 20)); // 128 KiB
    unsigned short* Mh16  = (unsigned short*)(W + (142u << 20)); // 1 MiB  (H,C,C) = Wq Wk^T/16
    unsigned short* WfT16 = (unsigned short*)(W + (143u << 20)); // 1 MiB  (H,C,C) = (Wv wp_h)^T

    const int M = BB * SS;                       // 16384
    const long long BSC = (long long)SS * CC;    // 131072
    const long long HBSC = (long long)BB * BSC;  // 4194304 (per-head qm stride)
    const long long CCC = (long long)CC * CC;    // 65536

    dim3 blk(256);

    // 0) weight precompute -------------------------------------------------
    cast3_kernel<<<dim3(512, 3), blk, 0, stream>>>(wq, wk, wv, wq16, wk16, wv16);
    ct_kernel<<<dim3((7 * CC) / 32, CC / 32, NCV), blk, 0, stream>>>(conv_w, convT, 7 * CC, CC);
    ct_kernel<<<dim3((NH * CC) / 32, CC / 32, 1), blk, 0, stream>>>(w_proj, wpT, NH * CC, CC);
    ct_kernel<<<dim3(CC / 32, CC / 32, 1), blk, 0, stream>>>(ff_w, ffT, CC, CC);
    ct_kernel<<<dim3(CC / 32, CC / 32, 1), blk, 0, stream>>>(ff2_w, ff2T, CC, CC);
    // Mh[h][d][d'] = sum_e Wq[h][d][e] Wk[h][d'][e] / 16
    gemm_mfma<<<dim3(2, 2, NH), blk, 0, stream>>>(
        wq16, CC, 0, CCC, wk16, CC, 0, CCC, Mh16, CC, 0, CCC,
        CC, 0, 0, nullptr, nullptr, 0.0625f, F_OUT16);
    // WfT[h][e'][d] = sum_e wp[h*256+e][e'] Wv[h][d][e]   (A = wpT slice, lda=2048)
    gemm_mfma<<<dim3(2, 2, NH), blk, 0, stream>>>(
        wpT, NH * CC, 0, CC, wv16, CC, 0, CCC, WfT16, CC, 0, CCC,
        CC, 0, 0, nullptr, nullptr, 1.0f, F_OUT16);

    // 1) positional encoding ----------------------------------------------
    const int T = M * CC;
    pe_add_kernel<<<T / 256, blk, 0, stream>>>(x, bufA, T);

    // 2) conv stack (f32 residual ping-pongs bufA <-> bufC) -----------------
    float* cur = bufA;
    float* alt = bufC;
    for (int k = 0; k < NCV; ++k) {
        ln16_kernel<<<M / 4, blk, 0, stream>>>(cur, ln_g, ln_b, h16);
        conv_mfma<<<dim3(M / 128, CC / 128), blk, 0, stream>>>(
            h16, convT + (size_t)k * (7 * CC) * CC, conv_b + k * CC, cur, alt);
        float* tmp = cur; cur = alt; alt = tmp;
    }
    // result in bufA

    // 3) attention ----------------------------------------------------------
    ln16_kernel<<<M / 4, blk, 0, stream>>>(bufA, ln_g, ln_b, h16);
    hipMemcpyAsync(bufC, bufA, (size_t)T * sizeof(float),
                   hipMemcpyDeviceToDevice, stream);   // residual seed; bufA dead after this

    // qm[h][b,t,d] = sum_d' h[b,t,d'] Mh[h][d][d']   (all heads, z=8)
    gemm_mfma<<<dim3(M / 128, CC / 128, NH), blk, 0, stream>>>(
        h16, CC, 0, 0, Mh16, CC, 0, CCC, qm16, CC, 0, HBSC,
        CC, 0, 0, nullptr, nullptr, 1.0f, F_OUT16);

    for (int g = 0; g < NH / 2; ++g) {           // 2 heads per group
        const long long scH = 32LL * SSS_;       // per-head stride in sc16
        const long long zTH = 32LL * BSC;        // per-head stride in zT16
        // scores[g2][b][s][t] = sum_d h[b,s,d] qm[2g+g2][b,t,d]   (z = g2*32+b)
        gemm_mfma<<<dim3(SS / 128, SS / 128, 64), blk, 0, stream>>>(
            h16, CC, BSC, 0,
            qm16 + (size_t)(2 * g) * HBSC, CC, BSC, HBSC,
            sc16, SS, SSS_, scH,
            CC, 5, 31, nullptr, nullptr, 1.0f, F_OUT16);
        // softmax over batch axis, both heads, in place (bf16)
        softmax2_kernel<<<(2 * SSS_) / 256, blk, 0, stream>>>(sc16);
        // zT[g2][b][c][s] = sum_d WfT[2g+g2][c][d] h[b,s,d]   (z = g2*32+b)
        gemm_mfma<<<dim3(CC / 128, SS / 128, 64), blk, 0, stream>>>(
            WfT16 + (size_t)(2 * g) * CCC, CC, 0, CCC,
            h16, CC, BSC, 0,
            zT16, SS, BSC, zTH,
            CC, 5, 31, nullptr, nullptr, 1.0f, F_OUT16);
        // bufC[b,s,c] += sum_t attn[g2][b,s,t] * zT[g2][b][c][t]  (per head, z=b)
        for (int g2 = 0; g2 < 2; ++g2) {
            gemm_mfma<<<dim3(SS / 128, CC / 128, BB), blk, 0, stream>>>(
                sc16 + (size_t)g2 * scH, SS, 0, SSS_,
                zT16 + (size_t)g2 * zTH, SS, 0, BSC,
                bufC, CC, 0, BSC,
                SS, 0, 0, nullptr, nullptr, 1.0f, F_ACCUM);
        }
    }

    // 4) feed-forward (residual = bufC) -------------------------------------
    ln16_kernel<<<M / 4, blk, 0, stream>>>(bufC, ln_g, ln_b, h16);
    gemm_mfma<<<dim3(M / 128, CC / 128, 1), blk, 0, stream>>>(
        h16, CC, 0, 0, ffT, CC, 0, 0, ff16, CC, 0, 0,
        CC, 0, 0, ff_b, nullptr, 1.0f, F_OUT16 | F_RELU);
    gemm_mfma<<<dim3(M / 128, CC / 128, 1), blk, 0, stream>>>(
        ff16, CC, 0, 0, ff2T, CC, 0, 0, out, CC, 0, 0,
        CC, 0, 0, ff2_b, bufC, 1.0f, 0);
}